// Round 2
// baseline (4244.259 us; speedup 1.0000x reference)
//
#include <hip/hip_runtime.h>
#include <stdint.h>

// ============================================================================
// LSTM (B=2048,T=256,D=32,H=256) + FC(256) on gfx950.
// R2: 64 persistent blocks x 512 threads (tileB=32 x all 1024 gate cols).
// Latency fixes vs R1 (which was 25x off MFMA floor, MfmaUtil 3.3%):
//  - 3-deep register pipeline for L2 weight-fragment loads (bb[3][8])
//  - next-step kt=0..2 weight loads issued at TOP of gate phase (t-invariant
//    addresses) so exp/rcp gate math hides their L2 latency
//  - obs x_{t+1} prefetched at loop top
//  - XOR chunk swizzle on the LDS A buffer (kills 4.6-way h-write conflicts)
//  - bias folded into accumulator init; raw v_rcp/v_exp2 gate math
// MFMA layouts (learn_hip verified): A[m=lane&15][k=(lane>>4)*8+j],
// B^T same, C/D: col=lane&15, row=(lane>>4)*4+reg.
// ============================================================================

typedef __attribute__((ext_vector_type(8))) short short8;
typedef __attribute__((ext_vector_type(4))) float f32x4;

#define LDSTRIDE 296  // 288 K-cols + 8 pad shorts (37 chunks of 8)

__device__ __forceinline__ short f2bf(float f) {
  uint32_t u = __builtin_bit_cast(uint32_t, f);
  u = (u + 0x7FFFu + ((u >> 16) & 1u)) >> 16;  // RNE
  return (short)(uint16_t)u;
}

__device__ __forceinline__ float fast_rcp(float x) { return __builtin_amdgcn_rcpf(x); }
__device__ __forceinline__ float fast_exp2(float x) { return __builtin_amdgcn_exp2f(x); }
#define LOG2E 1.4426950408889634f

__device__ __forceinline__ float sigmoidf_(float x) {
  return fast_rcp(1.0f + fast_exp2(-LOG2E * x));
}
__device__ __forceinline__ float tanhf_(float x) {
  // (t-1)/(t+1) with t=e^{2x}; exact at extremes (rcp(inf)=0 -> 1; t->0 -> -1)
  float t = fast_exp2((2.0f * LOG2E) * x);
  return 1.0f - 2.0f * fast_rcp(t + 1.0f);
}

// swizzled LDS index: col in shorts [0,296); chunk = 8 shorts (16B)
__device__ __forceinline__ int aidx(int row, int col) {
  return row * LDSTRIDE + ((((col >> 3) ^ ((row >> 2) & 3))) << 3) + (col & 7);
}

// ---------------------------------------------------------------------------
// Pack W_hh[1024x256] (K 0..255) and W_ih[1024x32] (K 256..287) into bf16
// fragment-major: frag (kt 0..8, ct 0..63), element (lane, j):
//   n = ct*16 + (lane&15), k = kt*32 + (lane>>4)*8 + j
// ---------------------------------------------------------------------------
__global__ void pack_w(const float* __restrict__ Whh, const float* __restrict__ Wih,
                       short* __restrict__ wpack) {
  int tid = blockIdx.x * 256 + threadIdx.x;  // 9*64*64 = 36864
  if (tid >= 9 * 64 * 64) return;
  int lane = tid & 63;
  int frag = tid >> 6;        // kt*64 + ct
  int ct = frag & 63, kt = frag >> 6;
  int n = ct * 16 + (lane & 15);
  int k0 = kt * 32 + (lane >> 4) * 8;
  short8 v;
#pragma unroll
  for (int j = 0; j < 8; ++j) {
    int k = k0 + j;
    float f = (k < 256) ? Whh[n * 256 + k] : Wih[n * 32 + (k - 256)];
    v[j] = f2bf(f);
  }
  *(short8*)(wpack + (size_t)frag * 512 + lane * 8) = v;
}

// W_fc[256x256] -> frags (kt 0..7, ct 0..15), same element mapping.
__global__ void pack_wfc(const float* __restrict__ Wfc, short* __restrict__ wfc) {
  int tid = blockIdx.x * 256 + threadIdx.x;  // 8*16*64 = 8192
  if (tid >= 8 * 16 * 64) return;
  int lane = tid & 63;
  int frag = tid >> 6;        // kt*16 + ct
  int ct = frag & 15, kt = frag >> 4;
  int n = ct * 16 + (lane & 15);
  int k0 = kt * 32 + (lane >> 4) * 8;
  short8 v;
#pragma unroll
  for (int j = 0; j < 8; ++j) v[j] = f2bf(Wfc[n * 256 + k0 + j]);
  *(short8*)(wfc + (size_t)frag * 512 + lane * 8) = v;
}

// ---------------------------------------------------------------------------
// Main persistent LSTM kernel. grid=64, block=512 (8 waves, 2/SIMD).
// Wave w owns col-tiles ct = w + 8q; q = g*2 + ui -> all 4 gates for hidden
// groups u = w, w+8. c[16] stays in VGPRs for all 256 steps.
// ---------------------------------------------------------------------------
__global__ __launch_bounds__(512, 2) void lstm_main(
    const float* __restrict__ obs, const short8* __restrict__ wpack,
    const short8* __restrict__ wfc, const float* __restrict__ b_ih,
    const float* __restrict__ b_hh, const float* __restrict__ b_fc,
    float* __restrict__ out) {
  __shared__ __align__(16) short A[32 * LDSTRIDE];  // [row][K=288 swizzled] bf16
  const int tid = threadIdx.x;
  const int w = tid >> 6;        // wave 0..7
  const int lane = tid & 63;
  const int l15 = lane & 15, quad = lane >> 4;
  const int row0 = blockIdx.x * 32;
  const int xr = tid >> 4, xdp = (tid & 15) * 2;  // x-staging assignment

  // h_0 = 0 (swizzle is a per-row bijection -> linear zero covers all)
  for (int i = tid; i < 32 * LDSTRIDE; i += 512) A[i] = 0;

  // fused gate bias; bias[q] matches acc[*][q] column block
  float bias[8];
#pragma unroll
  for (int g = 0; g < 4; ++g)
#pragma unroll
    for (int ui = 0; ui < 2; ++ui) {
      int idx = g * 256 + (w + ui * 8) * 16 + l15;
      bias[g * 2 + ui] = b_ih[idx] + b_hh[idx];
    }

  // stage x_0
  {
    const float2 x2 = *(const float2*)(obs + ((size_t)(row0 + xr) * 256 + 0) * 32 + xdp);
    A[aidx(xr, 256 + xdp)]     = f2bf(x2.x);
    A[aidx(xr, 256 + xdp + 1)] = f2bf(x2.y);
  }

  float c[16];  // c[r*8 + ui*4 + reg]
#pragma unroll
  for (int i = 0; i < 16; ++i) c[i] = 0.f;

  auto loadB = [&](int kt, short8* dst) {
#pragma unroll
    for (int q = 0; q < 8; ++q)
      dst[q] = wpack[(size_t)(kt * 64 + (w + 8 * q)) * 64 + lane];
  };

  // prime the 3-deep weight pipeline (in flight across the first barrier)
  short8 bb[3][8];
  loadB(0, bb[0]);
  loadB(1, bb[1]);
  loadB(2, bb[2]);

  __syncthreads();

  for (int t = 0; t < 256; ++t) {
    // prefetch x_{t+1} (consumed after barrier1); clamp last step in-bounds
    const int tn = (t < 255) ? (t + 1) : 255;
    const float2 x2 =
        *(const float2*)(obs + ((size_t)(row0 + xr) * 256 + tn) * 32 + xdp);

    f32x4 acc[2][8];
#pragma unroll
    for (int r = 0; r < 2; ++r)
#pragma unroll
      for (int q = 0; q < 8; ++q)
        acc[r][q] = (f32x4){bias[q], bias[q], bias[q], bias[q]};

    // GEMM: z[32 x 1024] = [h | x_t] @ [W_hh | W_ih]^T, K = 288 = 9*32
#pragma unroll
    for (int kt = 0; kt < 9; ++kt) {
      const short8 a0 = *(const short8*)&A[aidx(l15, kt * 32 + quad * 8)];
      const short8 a1 = *(const short8*)&A[aidx(16 + l15, kt * 32 + quad * 8)];
      const int s = kt % 3;
#pragma unroll
      for (int q = 0; q < 8; ++q) {
        acc[0][q] = __builtin_amdgcn_mfma_f32_16x16x32_bf16(a0, bb[s][q], acc[0][q], 0, 0, 0);
        acc[1][q] = __builtin_amdgcn_mfma_f32_16x16x32_bf16(a1, bb[s][q], acc[1][q], 0, 0, 0);
      }
      if (kt + 3 <= 8) loadB(kt + 3, bb[s]);  // refill consumed stage
    }
    __syncthreads();  // all waves done READING A for step t

    // issue next step's kt=0..2 weight loads FIRST; gate math hides latency
    loadB(0, bb[0]);
    loadB(1, bb[1]);
    loadB(2, bb[2]);

    // stage x_{t+1}
    A[aidx(xr, 256 + xdp)]     = f2bf(x2.x);
    A[aidx(xr, 256 + xdp + 1)] = f2bf(x2.y);

    // gates + state update; write h_{t+1} (bf16) into A
#pragma unroll
    for (int r = 0; r < 2; ++r)
#pragma unroll
      for (int ui = 0; ui < 2; ++ui) {
        f32x4 zi = acc[r][0 + ui], zf = acc[r][2 + ui];
        f32x4 zg = acc[r][4 + ui], zo = acc[r][6 + ui];
#pragma unroll
        for (int reg = 0; reg < 4; ++reg) {
          float iv = sigmoidf_(zi[reg]);
          float fv = sigmoidf_(zf[reg]);
          float gv = tanhf_(zg[reg]);
          float ov = sigmoidf_(zo[reg]);
          float cc = fv * c[r * 8 + ui * 4 + reg] + iv * gv;
          c[r * 8 + ui * 4 + reg] = cc;
          float hv = ov * tanhf_(cc);
          int row = r * 16 + quad * 4 + reg;
          int col = (w + ui * 8) * 16 + l15;
          A[aidx(row, col)] = f2bf(hv);
        }
      }
    __syncthreads();  // h_{t+1}/x_{t+1} visible before next K-loop
  }

  // FC epilogue: out[32 x 256] = h_last @ W_fc^T + b_fc, K = 256 = 8*32
  f32x4 ao[2][2];
#pragma unroll
  for (int r = 0; r < 2; ++r)
#pragma unroll
    for (int qi = 0; qi < 2; ++qi) ao[r][qi] = (f32x4){0.f, 0.f, 0.f, 0.f};
#pragma unroll
  for (int kt = 0; kt < 8; ++kt) {
    const short8 a0 = *(const short8*)&A[aidx(l15, kt * 32 + quad * 8)];
    const short8 a1 = *(const short8*)&A[aidx(16 + l15, kt * 32 + quad * 8)];
#pragma unroll
    for (int qi = 0; qi < 2; ++qi) {
      const short8 b = wfc[(size_t)(kt * 16 + (w + 8 * qi)) * 64 + lane];
      ao[0][qi] = __builtin_amdgcn_mfma_f32_16x16x32_bf16(a0, b, ao[0][qi], 0, 0, 0);
      ao[1][qi] = __builtin_amdgcn_mfma_f32_16x16x32_bf16(a1, b, ao[1][qi], 0, 0, 0);
    }
  }
#pragma unroll
  for (int qi = 0; qi < 2; ++qi) {
    const float bv = b_fc[(w + qi * 8) * 16 + l15];
#pragma unroll
    for (int r = 0; r < 2; ++r)
#pragma unroll
      for (int reg = 0; reg < 4; ++reg) {
        const int row = row0 + r * 16 + quad * 4 + reg;
        const int col = (w + qi * 8) * 16 + l15;
        out[(size_t)row * 256 + col] = ao[r][qi][reg] + bv;
      }
  }
}

extern "C" void kernel_launch(void* const* d_in, const int* in_sizes, int n_in,
                              void* d_out, int out_size, void* d_ws, size_t ws_size,
                              hipStream_t stream) {
  const float* obs  = (const float*)d_in[0];   // [2048,256,32]
  const float* W_ih = (const float*)d_in[1];   // [1024,32]
  const float* W_hh = (const float*)d_in[2];   // [1024,256]
  const float* b_ih = (const float*)d_in[3];   // [1024]
  const float* b_hh = (const float*)d_in[4];   // [1024]
  const float* W_fc = (const float*)d_in[5];   // [256,256]
  const float* b_fc = (const float*)d_in[6];   // [256]
  float* out = (float*)d_out;                  // [2048,256]

  short* wpack = (short*)d_ws;                 // 9*64*512 shorts = 576 KB
  short* wfcp  = wpack + 9 * 64 * 512;         // 8*16*512 shorts = 128 KB

  hipLaunchKernelGGL(pack_w, dim3(144), dim3(256), 0, stream, W_hh, W_ih, wpack);
  hipLaunchKernelGGL(pack_wfc, dim3(32), dim3(256), 0, stream, W_fc, wfcp);
  hipLaunchKernelGGL(lstm_main, dim3(64), dim3(512), 0, stream, obs,
                     (const short8*)wpack, (const short8*)wfcp,
                     b_ih, b_hh, b_fc, out);
}

// Round 3
// 3631.388 us; speedup vs baseline: 1.1688x; 1.1688x over previous
//
#include <hip/hip_runtime.h>
#include <stdint.h>

// ============================================================================
// LSTM (B=2048,T=256,D=32,H=256) + FC(256) on gfx950.
// R3: 256 blocks = 64 batch-tiles x 4 col-groups, 512 thr (8 waves).
// Block (bt,cg): batch rows bt*32..+32, gate cols for hidden slice cg*64..+64
// (all 4 gates). Wave w: rt=w>>2 (16-row half), hug=w&3 (16-hidden group),
// holds ALL its weights in VGPRs (4 gates x 9 ktiles = 36 frags = 144 VGPR)
// -> weights leave L2 once, not per step. Gate math fully in-lane (acc[g]).
// Per step, 4 sibling blocks exchange 4KB h-slices through L2 with
// agent-scope release/acquire flag sync (parity double-buffered).
// MFMA layouts (learn_hip verified): A[m=lane&15][k=(lane>>4)*8+j],
// B^T same, C/D: col=lane&15, row=(lane>>4)*4+reg.
// ============================================================================

typedef __attribute__((ext_vector_type(8))) short short8;
typedef __attribute__((ext_vector_type(4))) float f32x4;

#define LDSTRIDE 296  // 288 K-cols + 8 pad shorts: row stride 148 dw = 4 mod 32
#define NBT 64

__device__ __forceinline__ short f2bf(float f) {
  uint32_t u = __builtin_bit_cast(uint32_t, f);
  u = (u + 0x7FFFu + ((u >> 16) & 1u)) >> 16;  // RNE
  return (short)(uint16_t)u;
}

#define LOG2E 1.4426950408889634f
__device__ __forceinline__ float sigmoidf_(float x) {
  return __builtin_amdgcn_rcpf(1.0f + __builtin_amdgcn_exp2f(-LOG2E * x));
}
__device__ __forceinline__ float tanhf_(float x) {
  float t = __builtin_amdgcn_exp2f((2.0f * LOG2E) * x);
  return 1.0f - 2.0f * __builtin_amdgcn_rcpf(t + 1.0f);
}

__global__ void zero_flags(int* flags) {
  flags[threadIdx.x] = 0;  // 128 ints
}

// ---------------------------------------------------------------------------
// Pack W_hh[1024x256] (k 0..255) + W_ih[1024x32] (k 256..287) into bf16 frags.
// frag id = ((kt*4 + cg)*4 + hug)*4 + g ; element (lane,j):
//   n = g*256 + cg*64 + hug*16 + (lane&15), k = kt*32 + (lane>>4)*8 + j
// ---------------------------------------------------------------------------
__global__ void pack_w(const float* __restrict__ Whh, const float* __restrict__ Wih,
                       short* __restrict__ wpack) {
  int tid = blockIdx.x * 256 + threadIdx.x;  // 576 frags * 64 lanes
  if (tid >= 576 * 64) return;
  int lane = tid & 63;
  int frag = tid >> 6;
  int g = frag & 3, hug = (frag >> 2) & 3, cg = (frag >> 4) & 3, kt = frag >> 6;
  int n = g * 256 + cg * 64 + hug * 16 + (lane & 15);
  int k0 = kt * 32 + (lane >> 4) * 8;
  short8 v;
#pragma unroll
  for (int j = 0; j < 8; ++j) {
    int k = k0 + j;
    float f = (k < 256) ? Whh[n * 256 + k] : Wih[n * 32 + (k - 256)];
    v[j] = f2bf(f);
  }
  *(short8*)(wpack + (size_t)frag * 512 + lane * 8) = v;
}

// W_fc[256x256] -> frags (kt 0..7, ct 0..15): n = ct*16+(lane&15), k as above.
__global__ void pack_wfc(const float* __restrict__ Wfc, short* __restrict__ wfc) {
  int tid = blockIdx.x * 256 + threadIdx.x;  // 128 frags * 64 lanes
  if (tid >= 128 * 64) return;
  int lane = tid & 63;
  int frag = tid >> 6;
  int ct = frag & 15, kt = frag >> 4;
  int n = ct * 16 + (lane & 15);
  int k0 = kt * 32 + (lane >> 4) * 8;
  short8 v;
#pragma unroll
  for (int j = 0; j < 8; ++j) v[j] = f2bf(Wfc[n * 256 + k0 + j]);
  *(short8*)(wfc + (size_t)frag * 512 + lane * 8) = v;
}

// ---------------------------------------------------------------------------
// Main kernel: grid 256 = bt*4 + cg, block 512.
// ---------------------------------------------------------------------------
__global__ __launch_bounds__(512) void lstm_main(
    const float* __restrict__ obs, const short8* __restrict__ wpack,
    const short8* __restrict__ wfc, const float* __restrict__ b_ih,
    const float* __restrict__ b_hh, const float* __restrict__ b_fc,
    short* __restrict__ xchg, int* __restrict__ flags,
    float* __restrict__ out) {
  __shared__ __align__(16) short A[32 * LDSTRIDE];  // h cols 0..255, x 256..287
  const int tid = threadIdx.x;
  const int w = tid >> 6, lane = tid & 63;
  const int l15 = lane & 15, quad = lane >> 4;
  const int bt = blockIdx.x >> 2, cg = blockIdx.x & 3;
  const int rt = w >> 2, hug = w & 3;
  const int row0 = bt * 32;
  const int arow = rt * 16 + l15;           // A-frag row for GEMM
  const int xr = tid >> 4, xdp = (tid & 15) * 2;  // x staging assignment

  // zero A (h_0 = 0); barrier before x0 staging (different threads, same addrs)
  for (int i = tid; i < 32 * LDSTRIDE; i += 512) A[i] = 0;

  // persistent weight registers: 36 frags = 144 VGPR (constant indices only)
  short8 wfr[9][4];
#pragma unroll
  for (int kt = 0; kt < 9; ++kt)
#pragma unroll
    for (int g = 0; g < 4; ++g)
      wfr[kt][g] = wpack[(size_t)((((kt * 4 + cg) * 4 + hug) * 4 + g)) * 64 + lane];

  // fused bias per gate for this lane's hidden unit
  float bias[4];
#pragma unroll
  for (int g = 0; g < 4; ++g) {
    int idx = g * 256 + cg * 64 + hug * 16 + l15;
    bias[g] = b_ih[idx] + b_hh[idx];
  }

  float c4[4];
#pragma unroll
  for (int i = 0; i < 4; ++i) c4[i] = 0.f;

  __syncthreads();  // zero done
  // stage x_0
  {
    const float2 x2 = *(const float2*)(obs + ((size_t)(row0 + xr) * 256 + 0) * 32 + xdp);
    A[xr * LDSTRIDE + 256 + xdp] = f2bf(x2.x);
    A[xr * LDSTRIDE + 256 + xdp + 1] = f2bf(x2.y);
  }
  __syncthreads();

  for (int t = 0; t < 256; ++t) {
    // prefetch x_{t+1} (stored later this iteration)
    const int tn = (t < 255) ? (t + 1) : 255;
    const float2 x2 = *(const float2*)(obs + ((size_t)(row0 + xr) * 256 + tn) * 32 + xdp);

    f32x4 acc[4];
#pragma unroll
    for (int g = 0; g < 4; ++g)
      acc[g] = (f32x4){bias[g], bias[g], bias[g], bias[g]};

    // GEMM: z[16 x 64-cols-of-this-wave] over K=288 (h 0..255, x 256..287)
    short8 acur = *(const short8*)&A[arow * LDSTRIDE + quad * 8];
#pragma unroll
    for (int kt = 0; kt < 9; ++kt) {
      short8 anext;
      if (kt < 8) anext = *(const short8*)&A[arow * LDSTRIDE + (kt + 1) * 32 + quad * 8];
#pragma unroll
      for (int g = 0; g < 4; ++g)
        acc[g] = __builtin_amdgcn_mfma_f32_16x16x32_bf16(acur, wfr[kt][g], acc[g], 0, 0, 0);
      if (kt < 8) acur = anext;
    }

    // gates (all in-lane): rows quad*4+reg, hidden unit = hug*16+l15
    const int p = (t + 1) & 1;
    short* xg = xchg + (size_t)((p * NBT + bt) * 4 + cg) * (32 * 64);
    short hb[4];
#pragma unroll
    for (int reg = 0; reg < 4; ++reg) {
      float iv = sigmoidf_(acc[0][reg]);
      float fv = sigmoidf_(acc[1][reg]);
      float gv = tanhf_(acc[2][reg]);
      float ov = sigmoidf_(acc[3][reg]);
      float cc = fv * c4[reg] + iv * gv;
      c4[reg] = cc;
      hb[reg] = f2bf(ov * tanhf_(cc));
    }
    // own slice -> global exchange buffer (bf16) and local LDS
#pragma unroll
    for (int reg = 0; reg < 4; ++reg) {
      int row = rt * 16 + quad * 4 + reg;
      xg[row * 64 + hug * 16 + l15] = hb[reg];
      A[row * LDSTRIDE + cg * 64 + hug * 16 + l15] = hb[reg];
    }
    // stage x_{t+1}
    A[xr * LDSTRIDE + 256 + xdp] = f2bf(x2.x);
    A[xr * LDSTRIDE + 256 + xdp + 1] = f2bf(x2.y);

    __syncthreads();  // drains vmcnt: all global slice stores complete

    if (tid == 0) {
      int* f = &flags[bt * 2 + p];
      __hip_atomic_fetch_add(f, 1, __ATOMIC_RELEASE, __HIP_MEMORY_SCOPE_AGENT);
      const int target = 4 * ((t >> 1) + 1);
      while (__hip_atomic_load(f, __ATOMIC_ACQUIRE, __HIP_MEMORY_SCOPE_AGENT) < target) {
        __builtin_amdgcn_s_sleep(1);
      }
    }
    __syncthreads();  // flag acquired (L1/L2 invalidated) for whole CU

    // pull 3 sibling slices into LDS: row = tid>>4, 4 cols per thread
    {
      const int row = tid >> 4, c0 = (tid & 15) * 4;
#pragma unroll
      for (int s = 0; s < 3; ++s) {
        const int sib = (cg + 1 + s) & 3;
        const short* sg = xchg + (size_t)((p * NBT + bt) * 4 + sib) * (32 * 64);
        const short4 v = *(const short4*)(sg + row * 64 + c0);
        *(short4*)&A[row * LDSTRIDE + sib * 64 + c0] = v;
      }
    }
    __syncthreads();  // full h_{t+1} + x_{t+1} visible for next GEMM
  }

  // FC epilogue: out[32 x cg*64..+64] = h_last @ W_fc^T + b_fc
  // wave tile: rows rt*16..+16, cols (cg*4+hug)*16..+16
  f32x4 ao = (f32x4){0.f, 0.f, 0.f, 0.f};
#pragma unroll
  for (int kt = 0; kt < 8; ++kt) {
    const short8 a = *(const short8*)&A[arow * LDSTRIDE + kt * 32 + quad * 8];
    const short8 b = wfc[(size_t)(kt * 16 + cg * 4 + hug) * 64 + lane];
    ao = __builtin_amdgcn_mfma_f32_16x16x32_bf16(a, b, ao, 0, 0, 0);
  }
  {
    const int col = cg * 64 + hug * 16 + l15;
    const float bv = b_fc[col];
#pragma unroll
    for (int reg = 0; reg < 4; ++reg) {
      const int row = row0 + rt * 16 + quad * 4 + reg;
      out[(size_t)row * 256 + col] = ao[reg] + bv;
    }
  }
}

extern "C" void kernel_launch(void* const* d_in, const int* in_sizes, int n_in,
                              void* d_out, int out_size, void* d_ws, size_t ws_size,
                              hipStream_t stream) {
  const float* obs  = (const float*)d_in[0];   // [2048,256,32]
  const float* W_ih = (const float*)d_in[1];   // [1024,32]
  const float* W_hh = (const float*)d_in[2];   // [1024,256]
  const float* b_ih = (const float*)d_in[3];   // [1024]
  const float* b_hh = (const float*)d_in[4];   // [1024]
  const float* W_fc = (const float*)d_in[5];   // [256,256]
  const float* b_fc = (const float*)d_in[6];   // [256]
  float* out = (float*)d_out;                  // [2048,256]

  // ws layout
  int*   flags = (int*)d_ws;                       // 128 ints
  short* wpack = (short*)((char*)d_ws + 1024);     // 576*512 shorts = 576 KB
  short* wfcp  = wpack + 576 * 512;                // 128*512 shorts = 128 KB
  short* xchg  = wfcp + 128 * 512;                 // 2*64*4*2048 shorts = 2 MB

  hipLaunchKernelGGL(zero_flags, dim3(1), dim3(128), 0, stream, flags);
  hipLaunchKernelGGL(pack_w, dim3(144), dim3(256), 0, stream, W_hh, W_ih, wpack);
  hipLaunchKernelGGL(pack_wfc, dim3(32), dim3(256), 0, stream, W_fc, wfcp);
  hipLaunchKernelGGL(lstm_main, dim3(256), dim3(512), 0, stream, obs,
                     (const short8*)wpack, (const short8*)wfcp,
                     b_ih, b_hh, b_fc, xchg, flags, out);
}

// Round 4
// 922.590 us; speedup vs baseline: 4.6004x; 3.9361x over previous
//
#include <hip/hip_runtime.h>
#include <stdint.h>

// ============================================================================
// LSTM (B=2048,T=256,D=32,H=256) + FC(256) on gfx950.
// R4: 256 blocks = 128 batch-tiles x 2 col-groups, 512 thr (8 waves).
// Block (bt,cg): batch rows bt*16..+16, hidden slice cg*128..+128 (all 4
// gates = 512 gate cols). Wave w (0..7): hidden units cg*128 + w*16..+16,
// all 4 gates, all 16 rows; holds its 36 weight frags (9 ktiles x 4 gates)
// permanently in VGPRs (144 regs) -- __launch_bounds__(512,2) raises the
// compiler's pressure target to 256 so they actually STAY in registers
// (R3 failure: VGPR=112 proved demotion at default occupancy target).
// Per-step h exchange between the 2 siblings via RELAXED agent-scope 8B
// atomics (sc0/sc1 path to L3, NO acquire/release cache writeback/inv --
// R3's 266MB WRITE_SIZE / 530MB FETCH came from scope fences). Ordering:
// __syncthreads drains vmcnt before the flag add; all waves poll the flag;
// parity double-buffered slabs make WAR safe.
// MFMA layouts (learn_hip verified): A[m=lane&15][k=(lane>>4)*8+j],
// B^T same, C/D: col=lane&15, row=(lane>>4)*4+reg.
// ============================================================================

typedef __attribute__((ext_vector_type(8))) short short8;
typedef __attribute__((ext_vector_type(4))) float f32x4;
typedef unsigned long long ull;

#define LDSTRIDE 296  // 288 K-cols + 8 pad shorts
#define NBT 128       // batch tiles

__device__ __forceinline__ short f2bf(float f) {
  uint32_t u = __builtin_bit_cast(uint32_t, f);
  u = (u + 0x7FFFu + ((u >> 16) & 1u)) >> 16;  // RNE
  return (short)(uint16_t)u;
}

#define LOG2E 1.4426950408889634f
__device__ __forceinline__ float sigmoidf_(float x) {
  return __builtin_amdgcn_rcpf(1.0f + __builtin_amdgcn_exp2f(-LOG2E * x));
}
__device__ __forceinline__ float tanhf_(float x) {
  float t = __builtin_amdgcn_exp2f((2.0f * LOG2E) * x);
  return 1.0f - 2.0f * __builtin_amdgcn_rcpf(t + 1.0f);
}

__global__ void zero_flags(int* flags) { flags[threadIdx.x] = 0; }  // 256 ints

// ---------------------------------------------------------------------------
// Pack W_hh[1024x256] (k 0..255) + W_ih[1024x32] (k 256..287) into bf16 frags.
// frag = ((kt*2 + cg)*8 + hu)*4 + g ; element (lane,j):
//   n = g*256 + cg*128 + hu*16 + (lane&15), k = kt*32 + (lane>>4)*8 + j
// ---------------------------------------------------------------------------
__global__ void pack_w(const float* __restrict__ Whh, const float* __restrict__ Wih,
                       short* __restrict__ wpack) {
  int tid = blockIdx.x * 256 + threadIdx.x;  // 576 frags * 64 lanes
  if (tid >= 576 * 64) return;
  int lane = tid & 63;
  int frag = tid >> 6;
  int g = frag & 3, hu = (frag >> 2) & 7, cg = (frag >> 5) & 1, kt = frag >> 6;
  int n = g * 256 + cg * 128 + hu * 16 + (lane & 15);
  int k0 = kt * 32 + (lane >> 4) * 8;
  short8 v;
#pragma unroll
  for (int j = 0; j < 8; ++j) {
    int k = k0 + j;
    float f = (k < 256) ? Whh[n * 256 + k] : Wih[n * 32 + (k - 256)];
    v[j] = f2bf(f);
  }
  *(short8*)(wpack + (size_t)frag * 512 + lane * 8) = v;
}

// W_fc[256x256] -> frags (kt 0..7, ct 0..15): n = ct*16+(lane&15).
__global__ void pack_wfc(const float* __restrict__ Wfc, short* __restrict__ wfc) {
  int tid = blockIdx.x * 256 + threadIdx.x;  // 128 frags * 64 lanes
  if (tid >= 128 * 64) return;
  int lane = tid & 63;
  int frag = tid >> 6;
  int ct = frag & 15, kt = frag >> 4;
  int n = ct * 16 + (lane & 15);
  int k0 = kt * 32 + (lane >> 4) * 8;
  short8 v;
#pragma unroll
  for (int j = 0; j < 8; ++j) v[j] = f2bf(Wfc[n * 256 + k0 + j]);
  *(short8*)(wfc + (size_t)frag * 512 + lane * 8) = v;
}

// ---------------------------------------------------------------------------
// Main kernel: grid 256; bt = blockIdx>>1, cg = blockIdx&1; block 512.
// ---------------------------------------------------------------------------
__global__ __launch_bounds__(512, 2) void lstm_main(
    const float* __restrict__ obs, const short8* __restrict__ wpack,
    const short8* __restrict__ wfc, const float* __restrict__ b_ih,
    const float* __restrict__ b_hh, const float* __restrict__ b_fc,
    ull* __restrict__ xchg, int* __restrict__ flags,
    float* __restrict__ out) {
  __shared__ __align__(16) short A[16 * LDSTRIDE];  // h cols 0..255, x 256..287
  const int tid = threadIdx.x;
  const int w = tid >> 6, lane = tid & 63;
  const int l15 = lane & 15, quad = lane >> 4;
  const int bt = blockIdx.x >> 1, cg = blockIdx.x & 1;
  const int row0 = bt * 16;
  const int xr = tid >> 5, xd = tid & 31;  // x staging: row, d

  // zero A (h_0 = 0)
  for (int i = tid; i < 16 * LDSTRIDE; i += 512) A[i] = 0;

  // persistent weight registers: 36 frags = 144 VGPR (constant indices only)
  short8 wfr[9][4];
#pragma unroll
  for (int kt = 0; kt < 9; ++kt)
#pragma unroll
    for (int g = 0; g < 4; ++g)
      wfr[kt][g] = wpack[(size_t)(((kt * 2 + cg) * 8 + w) * 4 + g) * 64 + lane];

  // fused bias per gate for this lane's hidden unit (col = cg*128+w*16+l15)
  float bias[4];
#pragma unroll
  for (int g = 0; g < 4; ++g) {
    int idx = g * 256 + cg * 128 + w * 16 + l15;
    bias[g] = b_ih[idx] + b_hh[idx];
  }

  float c4[4];
#pragma unroll
  for (int i = 0; i < 4; ++i) c4[i] = 0.f;

  __syncthreads();
  // stage x_0 (one element per thread)
  A[xr * LDSTRIDE + 256 + xd] = f2bf(obs[((size_t)(row0 + xr) * 256 + 0) * 32 + xd]);
  __syncthreads();

  const int myflag = bt * 2;

  for (int t = 0; t < 256; ++t) {
    // prefetch x_{t+1}
    const int tn = (t < 255) ? (t + 1) : 255;
    const float xv = obs[((size_t)(row0 + xr) * 256 + tn) * 32 + xd];

    f32x4 acc[4];
#pragma unroll
    for (int g = 0; g < 4; ++g)
      acc[g] = (f32x4){bias[g], bias[g], bias[g], bias[g]};

    // GEMM: z[16 x 64] for this wave over K=288 (h 0..255, x 256..287)
    short8 acur = *(const short8*)&A[l15 * LDSTRIDE + quad * 8];
#pragma unroll
    for (int kt = 0; kt < 9; ++kt) {
      short8 anext;
      if (kt < 8) anext = *(const short8*)&A[l15 * LDSTRIDE + (kt + 1) * 32 + quad * 8];
#pragma unroll
      for (int g = 0; g < 4; ++g)
        acc[g] = __builtin_amdgcn_mfma_f32_16x16x32_bf16(acur, wfr[kt][g], acc[g], 0, 0, 0);
      if (kt < 8) acur = anext;
    }

    // gates (in-lane): rows quad*4+reg, hidden unit cg*128+w*16+l15
    short hb[4];
#pragma unroll
    for (int reg = 0; reg < 4; ++reg) {
      float iv = sigmoidf_(acc[0][reg]);
      float fv = sigmoidf_(acc[1][reg]);
      float gv = tanhf_(acc[2][reg]);
      float ov = sigmoidf_(acc[3][reg]);
      float cc = fv * c4[reg] + iv * gv;
      c4[reg] = cc;
      hb[reg] = f2bf(ov * tanhf_(cc));
    }

    // own slab -> L3 (relaxed agent 8B atomic store: sc0/sc1, no cache ops)
    const int p = (t + 1) & 1;
    ull hv = (ull)(uint16_t)hb[0] | ((ull)(uint16_t)hb[1] << 16) |
             ((ull)(uint16_t)hb[2] << 32) | ((ull)(uint16_t)hb[3] << 48);
    ull* slab = xchg + (size_t)((p * NBT + bt) * 2 + cg) * 512 + w * 64 + lane;
    __hip_atomic_store(slab, hv, __ATOMIC_RELAXED, __HIP_MEMORY_SCOPE_AGENT);

    __syncthreads();  // A-read phase done; vmcnt drained -> slab visible in L3

    if (tid == 0)
      __hip_atomic_fetch_add(&flags[myflag + p], 1, __ATOMIC_RELAXED,
                             __HIP_MEMORY_SCOPE_AGENT);
    const int target = 2 * ((t >> 1) + 1);
    while (__hip_atomic_load(&flags[myflag + p], __ATOMIC_RELAXED,
                             __HIP_MEMORY_SCOPE_AGENT) < target) {
    }

    // sibling slab load first (latency), then local LDS writes
    const ull* sslab =
        xchg + (size_t)((p * NBT + bt) * 2 + (cg ^ 1)) * 512 + w * 64 + lane;
    ull sv = __hip_atomic_load(sslab, __ATOMIC_RELAXED, __HIP_MEMORY_SCOPE_AGENT);

    // local h into A
#pragma unroll
    for (int reg = 0; reg < 4; ++reg)
      A[(quad * 4 + reg) * LDSTRIDE + cg * 128 + w * 16 + l15] = hb[reg];
    // x_{t+1} into A
    A[xr * LDSTRIDE + 256 + xd] = f2bf(xv);
    // sibling h into A
#pragma unroll
    for (int reg = 0; reg < 4; ++reg)
      A[(quad * 4 + reg) * LDSTRIDE + (cg ^ 1) * 128 + w * 16 + l15] =
          (short)(uint16_t)(sv >> (16 * reg));

    __syncthreads();  // full h_{t+1} + x_{t+1} visible for next GEMM
  }

  // FC epilogue: wave w -> out rows bt*16..+16, cols (cg*8+w)*16..+16
  f32x4 ao = (f32x4){0.f, 0.f, 0.f, 0.f};
  const int ct = cg * 8 + w;
#pragma unroll
  for (int kt = 0; kt < 8; ++kt) {
    const short8 a = *(const short8*)&A[l15 * LDSTRIDE + kt * 32 + quad * 8];
    const short8 b = wfc[(size_t)(kt * 16 + ct) * 64 + lane];
    ao = __builtin_amdgcn_mfma_f32_16x16x32_bf16(a, b, ao, 0, 0, 0);
  }
  {
    const int col = ct * 16 + l15;
    const float bv = b_fc[col];
#pragma unroll
    for (int reg = 0; reg < 4; ++reg) {
      const int row = row0 + quad * 4 + reg;
      out[(size_t)row * 256 + col] = ao[reg] + bv;
    }
  }
}

extern "C" void kernel_launch(void* const* d_in, const int* in_sizes, int n_in,
                              void* d_out, int out_size, void* d_ws, size_t ws_size,
                              hipStream_t stream) {
  const float* obs  = (const float*)d_in[0];   // [2048,256,32]
  const float* W_ih = (const float*)d_in[1];   // [1024,32]
  const float* W_hh = (const float*)d_in[2];   // [1024,256]
  const float* b_ih = (const float*)d_in[3];   // [1024]
  const float* b_hh = (const float*)d_in[4];   // [1024]
  const float* W_fc = (const float*)d_in[5];   // [256,256]
  const float* b_fc = (const float*)d_in[6];   // [256]
  float* out = (float*)d_out;                  // [2048,256]

  // ws layout
  int*   flags = (int*)d_ws;                       // 256 ints (1 KB)
  short* wpack = (short*)((char*)d_ws + 1024);     // 576*512 shorts = 576 KB
  short* wfcp  = wpack + 576 * 512;                // 128*512 shorts = 128 KB
  ull*   xchg  = (ull*)(wfcp + 128 * 512);         // 2*128*2*512*8B = 2 MB

  hipLaunchKernelGGL(zero_flags, dim3(1), dim3(256), 0, stream, flags);
  hipLaunchKernelGGL(pack_w, dim3(144), dim3(256), 0, stream, W_hh, W_ih, wpack);
  hipLaunchKernelGGL(pack_wfc, dim3(32), dim3(256), 0, stream, W_fc, wfcp);
  hipLaunchKernelGGL(lstm_main, dim3(256), dim3(512), 0, stream, obs,
                     (const short8*)wpack, (const short8*)wfcp,
                     b_ih, b_hh, b_fc, xchg, flags, out);
}